// Round 15
// baseline (723.168 us; speedup 1.0000x reference)
//
#include <hip/hip_runtime.h>
#include <hip/hip_bf16.h>
#include <math.h>

// ---------------------------------------------------------------------------
// Round 14: attn5 VALU diet (R14: 62us, VALUBusy 71% = bound). (1) fold
// 0.125*log2e into q8 at QK epilogue -> exp2f direct, no per-score muls;
// pad queries handled by zeroing q frags (z=0 -> exp2=1 uniform) — kills all
// inner-loop cndmasks. (2) kc loop split 0..10 / tail 11 — key masks & clamps
// only in tail. (3) Pb double-buffered — one lgkmcnt wait per step, not two.
// Everything else = R13. ws guard 191,365,120 B unchanged.
// ---------------------------------------------------------------------------

using bf16 = __hip_bfloat16;
typedef __attribute__((ext_vector_type(4))) float f32x4;
typedef long long i64;
typedef unsigned char uchar;

#define QSCALE 0.18033688011112042f   // 0.125 * log2(e)

static __device__ __forceinline__ float wave_sum64(float v){
  #pragma unroll
  for (int o = 32; o >= 1; o >>= 1) v += __shfl_xor(v, o, 64);
  return v;
}

static __device__ __forceinline__ void gl_lds16(const void* g, void* l){
  __builtin_amdgcn_global_load_lds((const __attribute__((address_space(1))) void*)g,
                                   (__attribute__((address_space(3))) void*)l, 16, 0, 0);
}

static __device__ __forceinline__ unsigned pack2(float a, float b){
  union { bf16 h[2]; unsigned u; } u;
  u.h[0] = __float2bfloat16(a); u.h[1] = __float2bfloat16(b);
  return u.u;
}

static __device__ __forceinline__ uchar f2f8(float v){
  return (uchar)(__builtin_amdgcn_cvt_pk_fp8_f32(v, 0.f, 0, false) & 0xff);
}
static __device__ __forceinline__ unsigned pack4_fp8(float a, float b, float c, float d){
  int v = __builtin_amdgcn_cvt_pk_fp8_f32(a, b, 0, false);
  v = __builtin_amdgcn_cvt_pk_fp8_f32(c, d, v, true);
  return (unsigned)v;
}

// merged weight prep: all 6 jobs fp8 transposed. 1280 blocks.
__global__ __launch_bounds__(256) void cvt_all(
    const float* s0, const float* s1, const float* s2, const float* s3,
    const float* s4, const float* s5,
    uchar* d0, uchar* d1, uchar* d2, uchar* d3, uchar* d4, uchar* d5)
{
  __shared__ float t[32][33];
  const float* srcs[6] = {s0, s1, s2, s3, s4, s5};
  uchar* dsts[6] = {d0, d1, d2, d3, d4, d5};
  const int Ks[6] = {256, 256, 256, 256, 256, 2048};
  const int Ns[6] = {256, 256, 256, 256, 2048, 256};
  const int offs[7] = {0, 64, 128, 192, 256, 768, 1280};
  int bid = blockIdx.x, j = 5;
  #pragma unroll
  for (int q = 4; q >= 0; q--) if (bid < offs[q + 1]) j = q;
  int local = bid - offs[j];
  int K = Ks[j], N = Ns[j];
  const float* src = srcs[j];
  uchar* dst = dsts[j];
  int kt = K >> 5;
  int kb = (local % kt) * 32, nb = (local / kt) * 32;
  int tx = threadIdx.x & 31, ty = threadIdx.x >> 5;
  #pragma unroll
  for (int dy = 0; dy < 32; dy += 8)
    t[ty + dy][tx] = src[(size_t)(kb + ty + dy) * N + nb + tx];
  __syncthreads();
  #pragma unroll
  for (int dy = 0; dy < 32; dy += 8)
    dst[(size_t)(nb + ty + dy) * K + kb + tx] = f2f8(t[tx][ty + dy]);
}

// embed + PE + scale -> x (bf16), LN1 -> fp8 xn8. one wave/row, grid 23040.
__global__ __launch_bounds__(256) void embed_ln1(
    const int* __restrict__ src, const float* __restrict__ emb,
    const float* __restrict__ na, const float* __restrict__ nb,
    bf16* __restrict__ x, uchar* __restrict__ xn8)
{
  int row  = blockIdx.x * 4 + (threadIdx.x >> 6);
  int lane = threadIdx.x & 63;
  int s = row % 360;
  int tok = src[row];
  float4 v = *(const float4*)(emb + (size_t)tok * 256 + lane * 4);
  float vv[4] = {v.x, v.y, v.z, v.w};
  if (s < 340){
    const float C = (-2.0f / 256.0f) * 13.287712379549449f;
    #pragma unroll
    for (int t = 0; t < 4; t++){
      int c = lane * 4 + t;
      float ang = (float)s * exp2f(C * (float)c);
      float pe = (c & 1) ? cosf(ang) : sinf(ang);
      vv[t] = 16.0f * vv[t] + pe;
    }
  }
  float sum = wave_sum64(vv[0] + vv[1] + vv[2] + vv[3]);
  float mu = sum * (1.0f / 256.0f);
  float d0 = vv[0]-mu, d1 = vv[1]-mu, d2 = vv[2]-mu, d3 = vv[3]-mu;
  float sq = wave_sum64(d0*d0 + d1*d1 + d2*d2 + d3*d3);
  float inv = 1.0f / (sqrtf(sq * (1.0f / 255.0f)) + 1e-6f);
  bf16 xo[4] = { __float2bfloat16(vv[0]), __float2bfloat16(vv[1]),
                 __float2bfloat16(vv[2]), __float2bfloat16(vv[3]) };
  *(uint2*)(x + (size_t)row * 256 + lane * 4) = *(uint2*)xo;
  float4 a4 = *(const float4*)(na + lane * 4);
  float4 b4 = *(const float4*)(nb + lane * 4);
  unsigned u = pack4_fp8(a4.x * d0 * inv + b4.x, a4.y * d1 * inv + b4.y,
                         a4.z * d2 * inv + b4.z, a4.w * d3 * inv + b4.w);
  *(unsigned*)(xn8 + (size_t)row * 256 + lane * 4) = u;
}

// LN2 over bf16 x -> fp8 xn8. one wave per row. grid 23040.
__global__ __launch_bounds__(256) void ln_k8(
    const bf16* __restrict__ x, const float* __restrict__ na,
    const float* __restrict__ nb, uchar* __restrict__ xn8)
{
  int row  = blockIdx.x * 4 + (threadIdx.x >> 6);
  int lane = threadIdx.x & 63;
  uint2 raw = *(const uint2*)(x + (size_t)row * 256 + lane * 4);
  bf16* xr = (bf16*)&raw;
  float v0 = __bfloat162float(xr[0]), v1 = __bfloat162float(xr[1]);
  float v2 = __bfloat162float(xr[2]), v3 = __bfloat162float(xr[3]);
  float sum = wave_sum64(v0 + v1 + v2 + v3);
  float mu = sum * (1.0f / 256.0f);
  float d0 = v0-mu, d1 = v1-mu, d2 = v2-mu, d3 = v3-mu;
  float sq = wave_sum64(d0*d0 + d1*d1 + d2*d2 + d3*d3);
  float inv = 1.0f / (sqrtf(sq * (1.0f / 255.0f)) + 1e-6f);
  float4 a4 = *(const float4*)(na + lane * 4);
  float4 b4 = *(const float4*)(nb + lane * 4);
  unsigned u = pack4_fp8(a4.x * d0 * inv + b4.x, a4.y * d1 * inv + b4.y,
                         a4.z * d2 * inv + b4.z, a4.w * d3 * inv + b4.w);
  *(unsigned*)(xn8 + (size_t)row * 256 + lane * 4) = u;
}

// fp8 GEMM, modes as R13. MODE4 region 0 (q) scaled by QSCALE.
template<int MODE>
__global__ __launch_bounds__(256) void gemm_f8(
    const uchar* __restrict__ A, int lda,
    const uchar* __restrict__ Bt, int ldb,
    const float* __restrict__ bias,
    uchar* __restrict__ out8, bf16* __restrict__ xres,
    int N, int K, int nTiles,
    const float* __restrict__ bq, const float* __restrict__ bk)
{
  __shared__ __align__(16) char smem[17408];
  uchar* As = (uchar*)smem;
  uchar* Bs = (uchar*)(smem + 8192);
  uchar* S8 = (uchar*)smem;
  bf16 (*Cs)[136] = (bf16 (*)[136])smem;
  int chunk = gridDim.x >> 3;
  int bi = (blockIdx.x & 7) * chunk + (blockIdx.x >> 3);
  int m0 = (bi / nTiles) * 128, n0 = (bi % nTiles) * 128;
  int tid = threadIdx.x;
  int wave = tid >> 6, lane = tid & 63;
  int wm = (wave >> 1) * 64, wn = (wave & 1) * 64;
  int r = lane & 15, qd = lane >> 4;

  const uchar* ag[2]; const uchar* bg[2]; uchar* la[2]; uchar* lb[2];
  #pragma unroll
  for (int j = 0; j < 2; j++){
    int c = tid + j * 256;
    int row = c >> 2, pp = c & 3;
    int lco = pp ^ ((row >> 1) & 3);
    ag[j] = A  + (size_t)(m0 + row) * lda + lco * 16;
    bg[j] = Bt + (size_t)(n0 + row) * ldb + lco * 16;
    la[j] = As + (size_t)c * 16;
    lb[j] = Bs + (size_t)c * 16;
  }

  f32x4 acc[4][4];
  #pragma unroll
  for (int mt = 0; mt < 4; mt++)
    #pragma unroll
    for (int nt = 0; nt < 4; nt++) acc[mt][nt] = (f32x4){0.f, 0.f, 0.f, 0.f};

  for (int k0 = 0; k0 < K; k0 += 64){
    #pragma unroll
    for (int j = 0; j < 2; j++){ gl_lds16(ag[j], la[j]); gl_lds16(bg[j], lb[j]); }
    #pragma unroll
    for (int j = 0; j < 2; j++){ ag[j] += 64; bg[j] += 64; }
    __syncthreads();
    #pragma unroll
    for (int ph = 0; ph < 2; ph++){
      int l16 = ph * 2 + (qd >> 1);
      int woff = (qd & 1) * 8;
      i64 af[4], bfr[4];
      #pragma unroll
      for (int t = 0; t < 4; t++){
        int rowA = wm + t * 16 + r;
        int rowB = wn + t * 16 + r;
        int swA = ((l16 ^ ((rowA >> 1) & 3)) * 16) + woff;
        int swB = ((l16 ^ ((rowB >> 1) & 3)) * 16) + woff;
        af[t]  = *(const i64*)(As + rowA * 64 + swA);
        bfr[t] = *(const i64*)(Bs + rowB * 64 + swB);
      }
      #pragma unroll
      for (int mt = 0; mt < 4; mt++)
        #pragma unroll
        for (int nt = 0; nt < 4; nt++){
          if (MODE == 5)
            acc[mt][nt] = __builtin_amdgcn_mfma_f32_16x16x32_fp8_fp8(af[mt], bfr[nt], acc[mt][nt], 0, 0, 0);
          else
            acc[mt][nt] = __builtin_amdgcn_mfma_f32_16x16x32_fp8_fp8(bfr[nt], af[mt], acc[mt][nt], 0, 0, 0);
        }
    }
    __syncthreads();
  }

  if (MODE == 2 || MODE == 4){
    const int region = (MODE == 4) ? (n0 >> 8) : 0;
    const float* bb = (MODE == 4) ? (region == 0 ? bq : bk) : bias;
    #pragma unroll
    for (int mt = 0; mt < 4; mt++)
      #pragma unroll
      for (int nt = 0; nt < 4; nt++){
        int ml  = wm + mt * 16 + r;
        int nl0 = wn + nt * 16 + qd * 4;
        int bidx = (MODE == 4) ? ((n0 & 255) + nl0) : (n0 + nl0);
        float v0 = acc[mt][nt][0] + bb[bidx + 0];
        float v1 = acc[mt][nt][1] + bb[bidx + 1];
        float v2 = acc[mt][nt][2] + bb[bidx + 2];
        float v3 = acc[mt][nt][3] + bb[bidx + 3];
        if (MODE == 2){
          v0 = fmaxf(v0, 0.f); v1 = fmaxf(v1, 0.f);
          v2 = fmaxf(v2, 0.f); v3 = fmaxf(v3, 0.f);
        }
        if (MODE == 4 && region == 0){       // q pre-scaled: exp2 path in attn
          v0 *= QSCALE; v1 *= QSCALE; v2 *= QSCALE; v3 *= QSCALE;
        }
        *(unsigned*)(S8 + ml * 136 + nl0) = pack4_fp8(v0, v1, v2, v3);
      }
    __syncthreads();
    int lr = tid >> 1, seg = tid & 1;
    #pragma unroll
    for (int j = 0; j < 4; j++){
      int nl = seg * 64 + j * 16;
      uint2 a = *(uint2*)(S8 + lr * 136 + nl);
      uint2 b = *(uint2*)(S8 + lr * 136 + nl + 8);
      uint4 st = make_uint4(a.x, a.y, b.x, b.y);
      if (MODE == 2){
        *(uint4*)(out8 + (size_t)(m0 + lr) * N + n0 + nl) = st;
      } else {
        int m = m0 + lr;
        int b_ = m / 360, s = m - b_ * 360;
        int nnl = (n0 & 255) + nl;
        int h = nnl >> 6, dk = nnl & 63;
        size_t roff = (region == 1) ? 23592960ull : 0ull;
        *(uint4*)(out8 + roff + ((size_t)(b_ * 4 + h) * 360 + s) * 64 + dk) = st;
      }
    }
  } else if (MODE == 5){
    #pragma unroll
    for (int mt = 0; mt < 4; mt++)
      #pragma unroll
      for (int nt = 0; nt < 4; nt++){
        int nl  = wn + nt * 16 + r;
        int ml0 = wm + mt * 16 + qd * 4;
        float bv_ = bias[n0 + nl];
        *(unsigned*)(S8 + nl * 136 + ml0) =
            pack4_fp8(acc[mt][nt][0] + bv_, acc[mt][nt][1] + bv_,
                      acc[mt][nt][2] + bv_, acc[mt][nt][3] + bv_);
      }
    __syncthreads();
    int nn = tid >> 1, part = tid & 1;
    int nnl = n0 + nn;
    int h = nnl >> 6, dk = nnl & 63;
    #pragma unroll
    for (int j0 = 0; j0 < 64; j0 += 8){
      int mm = m0 + part * 64 + j0;
      int b_ = mm / 360, s = mm - b_ * 360;
      uint2 val = *(uint2*)(S8 + nn * 136 + part * 64 + j0);
      *(uint2*)(out8 + ((size_t)((b_ * 4 + h) * 64 + dk)) * 360 + s) = val;
    }
  } else {  // MODE 3
    #pragma unroll
    for (int half = 0; half < 2; half++){
      if ((wave >> 1) == half){
        #pragma unroll
        for (int mt = 0; mt < 4; mt++)
          #pragma unroll
          for (int nt = 0; nt < 4; nt++){
            int ml  = mt * 16 + r;
            int nl0 = wn + nt * 16 + qd * 4;
            float v0 = acc[mt][nt][0] + bias[n0 + nl0 + 0];
            float v1 = acc[mt][nt][1] + bias[n0 + nl0 + 1];
            float v2 = acc[mt][nt][2] + bias[n0 + nl0 + 2];
            float v3 = acc[mt][nt][3] + bias[n0 + nl0 + 3];
            *(unsigned*)(&Cs[ml][nl0])     = pack2(v0, v1);
            *(unsigned*)(&Cs[ml][nl0 + 2]) = pack2(v2, v3);
          }
      }
      __syncthreads();
      int mbase = m0 + half * 64;
      int lr = tid >> 2, seg = tid & 3;
      bf16* op = xres + (size_t)(mbase + lr) * 256 + n0 + seg * 32;
      #pragma unroll
      for (int j = 0; j < 4; j++){
        uint4 cv = *(uint4*)(&Cs[lr][seg * 32 + j * 8]);
        uint4 xv = *(uint4*)(op + j * 8);
        bf16* ca = (bf16*)&cv; bf16* xa = (bf16*)&xv;
        bf16 o8[8];
        #pragma unroll
        for (int t = 0; t < 8; t++)
          o8[t] = __float2bfloat16(__bfloat162float(ca[t]) + __bfloat162float(xa[t]));
        *(uint4*)(op + j * 8) = *(uint4*)o8;
      }
      __syncthreads();
    }
  }
}

// attn5: fp8 flash attention, exp2 path (q pre-scaled), split kc loop,
// double-buffered P. one block per (b,h), 512 thr / 8 waves, 3 q-tiles/wave.
__global__ __launch_bounds__(512) void attn5(
    const uchar* __restrict__ q, const uchar* __restrict__ kk, const uchar* __restrict__ vt,
    const int* __restrict__ src, uchar* __restrict__ ctx8)
{
  __shared__ uchar Ks[360][80];
  __shared__ uchar Pb[2][8][16][48];
  __shared__ uchar Cb[8][16][80];
  int bh = blockIdx.x;
  int b = bh >> 2, h = bh & 3;
  int wave = threadIdx.x >> 6, lane = threadIdx.x & 63;
  int r = lane & 15, qd = lane >> 4;
  const uchar* qb = q  + (size_t)bh * 360 * 64;
  const uchar* kb = kk + (size_t)bh * 360 * 64;
  const uchar* vb = vt + (size_t)bh * 64 * 360;
  const int* srow = src + b * 360;

  for (int c = threadIdx.x; c < 1440; c += 512){
    int row = c >> 2, g = c & 3;
    *(uint4*)(&Ks[row][g * 16]) = *(const uint4*)(kb + row * 64 + g * 16);
  }
  __syncthreads();

  i64 qa0[3], qa1[3];
  float lsum[3];
  f32x4 accO[3][4];
  #pragma unroll
  for (int tl = 0; tl < 3; tl++){
    int qt = wave * 3 + tl;
    int qg = qt * 16 + r;
    int qrow = qg > 359 ? 359 : qg;
    bool qp = (qg < 360) && (srow[qg] == 799);   // PAD query -> zero q: z=0, exp2=1
    qa0[tl] = qp ? 0 : *(const i64*)(qb + qrow * 64 + qd * 8);
    qa1[tl] = qp ? 0 : *(const i64*)(qb + qrow * 64 + 32 + qd * 8);
    lsum[tl] = 0.f;
    #pragma unroll
    for (int dt = 0; dt < 4; dt++) accO[tl][dt] = (f32x4){0.f, 0.f, 0.f, 0.f};
  }

  int pb = 0;
  // ---- main: kc 0..10 (keys < 352: no masks, no clamps) ----
  for (int kc = 0; kc < 11; kc++){
    i64 kf00 = *(const i64*)(&Ks[kc * 32 + r][qd * 8]);
    i64 kf01 = *(const i64*)(&Ks[kc * 32 + r][32 + qd * 8]);
    i64 kf10 = *(const i64*)(&Ks[kc * 32 + 16 + r][qd * 8]);
    i64 kf11 = *(const i64*)(&Ks[kc * 32 + 16 + r][32 + qd * 8]);
    i64 vf[4];
    #pragma unroll
    for (int dt = 0; dt < 4; dt++)
      vf[dt] = *(const i64*)(vb + (size_t)(dt * 16 + r) * 360 + kc * 32 + qd * 8);

    #pragma unroll
    for (int tl = 0; tl < 3; tl++){
      f32x4 z0 = {0.f, 0.f, 0.f, 0.f}, z1 = {0.f, 0.f, 0.f, 0.f};
      z0 = __builtin_amdgcn_mfma_f32_16x16x32_fp8_fp8(kf00, qa0[tl], z0, 0, 0, 0);
      z0 = __builtin_amdgcn_mfma_f32_16x16x32_fp8_fp8(kf01, qa1[tl], z0, 0, 0, 0);
      z1 = __builtin_amdgcn_mfma_f32_16x16x32_fp8_fp8(kf10, qa0[tl], z1, 0, 0, 0);
      z1 = __builtin_amdgcn_mfma_f32_16x16x32_fp8_fp8(kf11, qa1[tl], z1, 0, 0, 0);
      float p0[4], p1[4];
      #pragma unroll
      for (int i = 0; i < 4; i++){
        p0[i] = exp2f(z0[i]);
        p1[i] = exp2f(z1[i]);
        lsum[tl] += p0[i] + p1[i];
      }
      *(unsigned*)(&Pb[pb][wave][r][qd * 4])      = pack4_fp8(p0[0], p0[1], p0[2], p0[3]);
      *(unsigned*)(&Pb[pb][wave][r][16 + qd * 4]) = pack4_fp8(p1[0], p1[1], p1[2], p1[3]);
      asm volatile("s_waitcnt lgkmcnt(0)" ::: "memory");
      i64 pa = *(const i64*)(&Pb[pb][wave][r][qd * 8]);
      #pragma unroll
      for (int dt = 0; dt < 4; dt++)
        accO[tl][dt] = __builtin_amdgcn_mfma_f32_16x16x32_fp8_fp8(pa, vf[dt], accO[tl][dt], 0, 0, 0);
      pb ^= 1;                                   // WAR handled by double buffer
    }
  }
  // ---- tail: kc = 11 (keys 352..383; mask >=360) ----
  {
    int krow0 = 352 + r;                 // < 360 for r<8
    if (krow0 > 359) krow0 = 359;
    i64 kf00 = *(const i64*)(&Ks[krow0][qd * 8]);
    i64 kf01 = *(const i64*)(&Ks[krow0][32 + qd * 8]);
    i64 vf[4];
    #pragma unroll
    for (int dt = 0; dt < 4; dt++)
      vf[dt] = *(const i64*)(vb + (size_t)(dt * 16 + r) * 360 + 352 + qd * 8);

    #pragma unroll
    for (int tl = 0; tl < 3; tl++){
      f32x4 z0 = {0.f, 0.f, 0.f, 0.f};
      z0 = __builtin_amdgcn_mfma_f32_16x16x32_fp8_fp8(kf00, qa0[tl], z0, 0, 0, 0);
      z0 = __builtin_amdgcn_mfma_f32_16x16x32_fp8_fp8(kf01, qa1[tl], z0, 0, 0, 0);
      float p0[4];
      #pragma unroll
      for (int i = 0; i < 4; i++){
        int key = 352 + qd * 4 + i;
        p0[i] = (key < 360) ? exp2f(z0[i]) : 0.0f;
        lsum[tl] += p0[i];
      }
      *(unsigned*)(&Pb[pb][wave][r][qd * 4])      = pack4_fp8(p0[0], p0[1], p0[2], p0[3]);
      *(unsigned*)(&Pb[pb][wave][r][16 + qd * 4]) = 0u;     // keys 368..383 = 0
      asm volatile("s_waitcnt lgkmcnt(0)" ::: "memory");
      i64 pa = *(const i64*)(&Pb[pb][wave][r][qd * 8]);
      #pragma unroll
      for (int dt = 0; dt < 4; dt++)
        accO[tl][dt] = __builtin_amdgcn_mfma_f32_16x16x32_fp8_fp8(pa, vf[dt], accO[tl][dt], 0, 0, 0);
      pb ^= 1;
    }
  }

  #pragma unroll
  for (int tl = 0; tl < 3; tl++){
    int qt = wave * 3 + tl;
    float ls = lsum[tl];
    ls += __shfl_xor(ls, 16, 64);
    ls += __shfl_xor(ls, 32, 64);
    float invl = 1.0f / ls;
    #pragma unroll
    for (int i = 0; i < 4; i++){
      float inv_i = __shfl(invl, qd * 4 + i, 64);
      #pragma unroll
      for (int dt = 0; dt < 4; dt++)
        Cb[wave][qd * 4 + i][dt * 16 + r] = f2f8(accO[tl][dt][i] * inv_i);
    }
    asm volatile("s_waitcnt lgkmcnt(0)" ::: "memory");
    int qglob = qt * 16 + r;
    if (qglob < 360)
      *(uint4*)(ctx8 + ((size_t)(b * 360 + qglob)) * 256 + h * 64 + qd * 16) =
          *(uint4*)(&Cb[wave][r][qd * 16]);
    asm volatile("s_waitcnt lgkmcnt(0)" ::: "memory");
  }
}

// head: one block per batch (grid 256, 4 waves).
__global__ __launch_bounds__(256) void head_k(
    const bf16* __restrict__ x, const int* __restrict__ src,
    const float* __restrict__ wl, const float* __restrict__ bl,
    float* __restrict__ out)
{
  __shared__ bf16 Xs[192][264];
  int b = blockIdx.x;
  int tid = threadIdx.x;
  int wave = tid >> 6, lane = tid & 63;
  int g = lane >> 3, sub = lane & 7;

  const bf16* xb = x + (size_t)b * 360 * 256;
  for (int it = 0; it < 24; it++){
    int idx = tid + it * 256;
    int row = idx >> 5, col = idx & 31;
    *(uint4*)(&Xs[row][col * 8]) = *(const uint4*)(xb + row * 256 + col * 8);
  }

  float wv[96];
  {
    const float4* wr4 = (const float4*)(wl + (size_t)(g * 256 + sub * 32) * 3);
    #pragma unroll
    for (int c = 0; c < 24; c++) *(float4*)(&wv[c * 4]) = wr4[c];
  }
  float bl0 = bl[0], bl1 = bl[1], bl2 = bl[2];
  const int* sr = src + b * 360;
  __syncthreads();

  for (int p = wave; p < 91; p += 4){
    int i = 0, rem = p;
    while (rem >= 13 - i){ rem -= 13 - i; i++; }
    int j = i + 1 + rem;
    int base = 12 * i - (i * (i - 1)) / 2;
    int pe = base + (j - i) - 1;
    int eb = 28 + 2 * pe;

    int idxg;
    if (g == 0) idxg = 2 * i;
    else if (g == 1) idxg = 2 * i + 1;
    else if (g == 2) idxg = 2 * j;
    else if (g == 3) idxg = 2 * j + 1;
    else idxg = eb + (g - 4);
    bool zm = !(g >= 4 && j == 13);

    uint4 xv[4];
    #pragma unroll
    for (int c = 0; c < 4; c++) xv[c] = *(uint4*)(&Xs[idxg][sub * 32 + c * 8]);
    const bf16* xa = (const bf16*)xv;
    float a0 = 0.f, a1 = 0.f, a2 = 0.f;
    #pragma unroll
    for (int t = 0; t < 32; t++){
      float f = zm ? __bfloat162float(xa[t]) : 0.0f;
      a0 += f * wv[t * 3 + 0];
      a1 += f * wv[t * 3 + 1];
      a2 += f * wv[t * 3 + 2];
    }
    #pragma unroll
    for (int o = 1; o < 64; o <<= 1){
      a0 += __shfl_xor(a0, o, 64);
      a1 += __shfl_xor(a1, o, 64);
      a2 += __shfl_xor(a2, o, 64);
    }
    if (lane == 0){
      int ti = sr[2 * i], ai = sr[2 * i + 1], tj = sr[2 * j], aj = sr[2 * j + 1];
      bool c1 = (ai == 2) || (aj == 2);
      bool c2 = (tj == 1) || (ai == 1) || (aj == 1);
      bool c3 = (ti == 799) || (tj == 799) || (ai == 0) || (aj == 0);
      bool c4 = false;
      if (j < 13){
        int es = 28 + 4 * pe;
        c4 = (sr[es] == 1) || (sr[es + 1] == 1) || (sr[es + 2] == 1) || (sr[es + 3] == 1);
      }
      bool m1 = c3 || c4, m2 = m1 || c2, m3 = m2 || c1;
      float* op = out + ((size_t)b * 91 + p) * 3;
      op[0] = m1 ? -1.0e9f : (a0 + bl0);
      op[1] = m2 ? -1.0e9f : (a1 + bl1);
      op[2] = m3 ? -1.0e9f : (a2 + bl2);
    }
  }
}

extern "C" void kernel_launch(void* const* d_in, const int* in_sizes, int n_in,
                              void* d_out, int out_size, void* d_ws, size_t ws_size,
                              hipStream_t stream)
{
  const int*   src = (const int*)  d_in[0];
  const float* emb = (const float*)d_in[1];
  const float* wq  = (const float*)d_in[2];  const float* bq = (const float*)d_in[3];
  const float* wk  = (const float*)d_in[4];  const float* bk = (const float*)d_in[5];
  const float* wv  = (const float*)d_in[6];  const float* bv = (const float*)d_in[7];
  const float* wo  = (const float*)d_in[8];  const float* bo = (const float*)d_in[9];
  const float* n1a = (const float*)d_in[10]; const float* n1b = (const float*)d_in[11];
  const float* n2a = (const float*)d_in[12]; const float* n2b = (const float*)d_in[13];
  const float* w1  = (const float*)d_in[14]; const float* b1 = (const float*)d_in[15];
  const float* w2  = (const float*)d_in[16]; const float* b2 = (const float*)d_in[17];
  const float* wl  = (const float*)d_in[18]; const float* bl = (const float*)d_in[19];
  float* out = (float*)d_out;

  if (ws_size < 191365120ull) return;

  char* ws = (char*)d_ws;
  bf16*  x    = (bf16*)(ws);
  uchar* xn8  = (uchar*)(ws + 47185920ull);
  char*  R    = ws + 70778880ull;
  uchar* q8   = (uchar*)(R);
  uchar* vt8  = (uchar*)(R + 47185920ull);
  uchar* h8   = (uchar*)(R);
  char*  wC   = ws + 141557760ull;
  uchar* wqkv8 = (uchar*)(wC);
  uchar* wo8   = (uchar*)(wC + 196608);
  uchar* w1f8T = (uchar*)(wC + 262144);
  uchar* w2f8T = (uchar*)(wC + 786432);

  cvt_all<<<1280, 256, 0, stream>>>(wq, wk, wv, wo, w1, w2,
                                    wqkv8, wqkv8 + 65536, wqkv8 + 131072,
                                    wo8, w1f8T, w2f8T);

  embed_ln1<<<23040, 256, 0, stream>>>(src, emb, n1a, n1b, x, xn8);

  gemm_f8<4><<<2880, 256, 0, stream>>>(xn8, 256, wqkv8, 256, nullptr, q8, nullptr,
                                       512, 256, 4, bq, bk);
  gemm_f8<5><<<1440, 256, 0, stream>>>(xn8, 256, wqkv8 + 131072, 256, bv, vt8, nullptr,
                                       256, 256, 2, nullptr, nullptr);

  attn5<<<1024, 512, 0, stream>>>(q8, q8 + 23592960ull, vt8, src, xn8 /* ctx8 */);

  gemm_f8<3><<<1440, 256, 0, stream>>>(xn8, 256, wo8, 256, bo, nullptr, x,
                                       256, 256, 2, nullptr, nullptr);

  ln_k8<<<23040, 256, 0, stream>>>(x, n2a, n2b, xn8);

  for (int mc = 0; mc < 4; mc++){
    const uchar* xnc = xn8 + (size_t)mc * 23040 * 256;
    bf16* xc = x + (size_t)mc * 23040 * 256;
    gemm_f8<2><<<2880, 256, 0, stream>>>(xnc, 256, w1f8T, 256, b1, h8, nullptr,
                                         2048, 256, 16, nullptr, nullptr);
    gemm_f8<3><<<360, 256, 0, stream>>>(h8, 2048, w2f8T, 2048, b2, nullptr, xc,
                                        256, 2048, 2, nullptr, nullptr);
  }

  head_k<<<256, 256, 0, stream>>>(x, src, wl, bl, out);
}

// Round 16
// 721.479 us; speedup vs baseline: 1.0023x; 1.0023x over previous
//
#include <hip/hip_runtime.h>
#include <hip/hip_bf16.h>
#include <math.h>

// ---------------------------------------------------------------------------
// Round 15: un-spill attn5. R15 regression (62->97us): double-buffered Pb
// (runtime pb) + removed trailing lgkmcnt let the scheduler inflate live
// ranges -> VGPR 64->128 + scratch spill (WRITE 23->80MB). Restore single Pb
// + both waits (R13 structure), KEEP exp2/QSCALE fold, pad-q zeroing, split
// kc loop (VALU wins with no live-state cost). Everything else = R15.
// ws guard 191,365,120 B unchanged.
// ---------------------------------------------------------------------------

using bf16 = __hip_bfloat16;
typedef __attribute__((ext_vector_type(4))) float f32x4;
typedef long long i64;
typedef unsigned char uchar;

#define QSCALE 0.18033688011112042f   // 0.125 * log2(e)

static __device__ __forceinline__ float wave_sum64(float v){
  #pragma unroll
  for (int o = 32; o >= 1; o >>= 1) v += __shfl_xor(v, o, 64);
  return v;
}

static __device__ __forceinline__ void gl_lds16(const void* g, void* l){
  __builtin_amdgcn_global_load_lds((const __attribute__((address_space(1))) void*)g,
                                   (__attribute__((address_space(3))) void*)l, 16, 0, 0);
}

static __device__ __forceinline__ unsigned pack2(float a, float b){
  union { bf16 h[2]; unsigned u; } u;
  u.h[0] = __float2bfloat16(a); u.h[1] = __float2bfloat16(b);
  return u.u;
}

static __device__ __forceinline__ uchar f2f8(float v){
  return (uchar)(__builtin_amdgcn_cvt_pk_fp8_f32(v, 0.f, 0, false) & 0xff);
}
static __device__ __forceinline__ unsigned pack4_fp8(float a, float b, float c, float d){
  int v = __builtin_amdgcn_cvt_pk_fp8_f32(a, b, 0, false);
  v = __builtin_amdgcn_cvt_pk_fp8_f32(c, d, v, true);
  return (unsigned)v;
}

// merged weight prep: all 6 jobs fp8 transposed. 1280 blocks.
__global__ __launch_bounds__(256) void cvt_all(
    const float* s0, const float* s1, const float* s2, const float* s3,
    const float* s4, const float* s5,
    uchar* d0, uchar* d1, uchar* d2, uchar* d3, uchar* d4, uchar* d5)
{
  __shared__ float t[32][33];
  const float* srcs[6] = {s0, s1, s2, s3, s4, s5};
  uchar* dsts[6] = {d0, d1, d2, d3, d4, d5};
  const int Ks[6] = {256, 256, 256, 256, 256, 2048};
  const int Ns[6] = {256, 256, 256, 256, 2048, 256};
  const int offs[7] = {0, 64, 128, 192, 256, 768, 1280};
  int bid = blockIdx.x, j = 5;
  #pragma unroll
  for (int q = 4; q >= 0; q--) if (bid < offs[q + 1]) j = q;
  int local = bid - offs[j];
  int K = Ks[j], N = Ns[j];
  const float* src = srcs[j];
  uchar* dst = dsts[j];
  int kt = K >> 5;
  int kb = (local % kt) * 32, nb = (local / kt) * 32;
  int tx = threadIdx.x & 31, ty = threadIdx.x >> 5;
  #pragma unroll
  for (int dy = 0; dy < 32; dy += 8)
    t[ty + dy][tx] = src[(size_t)(kb + ty + dy) * N + nb + tx];
  __syncthreads();
  #pragma unroll
  for (int dy = 0; dy < 32; dy += 8)
    dst[(size_t)(nb + ty + dy) * K + kb + tx] = f2f8(t[tx][ty + dy]);
}

// embed + PE + scale -> x (bf16), LN1 -> fp8 xn8. one wave/row, grid 23040.
__global__ __launch_bounds__(256) void embed_ln1(
    const int* __restrict__ src, const float* __restrict__ emb,
    const float* __restrict__ na, const float* __restrict__ nb,
    bf16* __restrict__ x, uchar* __restrict__ xn8)
{
  int row  = blockIdx.x * 4 + (threadIdx.x >> 6);
  int lane = threadIdx.x & 63;
  int s = row % 360;
  int tok = src[row];
  float4 v = *(const float4*)(emb + (size_t)tok * 256 + lane * 4);
  float vv[4] = {v.x, v.y, v.z, v.w};
  if (s < 340){
    const float C = (-2.0f / 256.0f) * 13.287712379549449f;
    #pragma unroll
    for (int t = 0; t < 4; t++){
      int c = lane * 4 + t;
      float ang = (float)s * exp2f(C * (float)c);
      float pe = (c & 1) ? cosf(ang) : sinf(ang);
      vv[t] = 16.0f * vv[t] + pe;
    }
  }
  float sum = wave_sum64(vv[0] + vv[1] + vv[2] + vv[3]);
  float mu = sum * (1.0f / 256.0f);
  float d0 = vv[0]-mu, d1 = vv[1]-mu, d2 = vv[2]-mu, d3 = vv[3]-mu;
  float sq = wave_sum64(d0*d0 + d1*d1 + d2*d2 + d3*d3);
  float inv = 1.0f / (sqrtf(sq * (1.0f / 255.0f)) + 1e-6f);
  bf16 xo[4] = { __float2bfloat16(vv[0]), __float2bfloat16(vv[1]),
                 __float2bfloat16(vv[2]), __float2bfloat16(vv[3]) };
  *(uint2*)(x + (size_t)row * 256 + lane * 4) = *(uint2*)xo;
  float4 a4 = *(const float4*)(na + lane * 4);
  float4 b4 = *(const float4*)(nb + lane * 4);
  unsigned u = pack4_fp8(a4.x * d0 * inv + b4.x, a4.y * d1 * inv + b4.y,
                         a4.z * d2 * inv + b4.z, a4.w * d3 * inv + b4.w);
  *(unsigned*)(xn8 + (size_t)row * 256 + lane * 4) = u;
}

// LN2 over bf16 x -> fp8 xn8. one wave per row. grid 23040.
__global__ __launch_bounds__(256) void ln_k8(
    const bf16* __restrict__ x, const float* __restrict__ na,
    const float* __restrict__ nb, uchar* __restrict__ xn8)
{
  int row  = blockIdx.x * 4 + (threadIdx.x >> 6);
  int lane = threadIdx.x & 63;
  uint2 raw = *(const uint2*)(x + (size_t)row * 256 + lane * 4);
  bf16* xr = (bf16*)&raw;
  float v0 = __bfloat162float(xr[0]), v1 = __bfloat162float(xr[1]);
  float v2 = __bfloat162float(xr[2]), v3 = __bfloat162float(xr[3]);
  float sum = wave_sum64(v0 + v1 + v2 + v3);
  float mu = sum * (1.0f / 256.0f);
  float d0 = v0-mu, d1 = v1-mu, d2 = v2-mu, d3 = v3-mu;
  float sq = wave_sum64(d0*d0 + d1*d1 + d2*d2 + d3*d3);
  float inv = 1.0f / (sqrtf(sq * (1.0f / 255.0f)) + 1e-6f);
  float4 a4 = *(const float4*)(na + lane * 4);
  float4 b4 = *(const float4*)(nb + lane * 4);
  unsigned u = pack4_fp8(a4.x * d0 * inv + b4.x, a4.y * d1 * inv + b4.y,
                         a4.z * d2 * inv + b4.z, a4.w * d3 * inv + b4.w);
  *(unsigned*)(xn8 + (size_t)row * 256 + lane * 4) = u;
}

// fp8 GEMM, modes as R13. MODE4 region 0 (q) scaled by QSCALE.
template<int MODE>
__global__ __launch_bounds__(256) void gemm_f8(
    const uchar* __restrict__ A, int lda,
    const uchar* __restrict__ Bt, int ldb,
    const float* __restrict__ bias,
    uchar* __restrict__ out8, bf16* __restrict__ xres,
    int N, int K, int nTiles,
    const float* __restrict__ bq, const float* __restrict__ bk)
{
  __shared__ __align__(16) char smem[17408];
  uchar* As = (uchar*)smem;
  uchar* Bs = (uchar*)(smem + 8192);
  uchar* S8 = (uchar*)smem;
  bf16 (*Cs)[136] = (bf16 (*)[136])smem;
  int chunk = gridDim.x >> 3;
  int bi = (blockIdx.x & 7) * chunk + (blockIdx.x >> 3);
  int m0 = (bi / nTiles) * 128, n0 = (bi % nTiles) * 128;
  int tid = threadIdx.x;
  int wave = tid >> 6, lane = tid & 63;
  int wm = (wave >> 1) * 64, wn = (wave & 1) * 64;
  int r = lane & 15, qd = lane >> 4;

  const uchar* ag[2]; const uchar* bg[2]; uchar* la[2]; uchar* lb[2];
  #pragma unroll
  for (int j = 0; j < 2; j++){
    int c = tid + j * 256;
    int row = c >> 2, pp = c & 3;
    int lco = pp ^ ((row >> 1) & 3);
    ag[j] = A  + (size_t)(m0 + row) * lda + lco * 16;
    bg[j] = Bt + (size_t)(n0 + row) * ldb + lco * 16;
    la[j] = As + (size_t)c * 16;
    lb[j] = Bs + (size_t)c * 16;
  }

  f32x4 acc[4][4];
  #pragma unroll
  for (int mt = 0; mt < 4; mt++)
    #pragma unroll
    for (int nt = 0; nt < 4; nt++) acc[mt][nt] = (f32x4){0.f, 0.f, 0.f, 0.f};

  for (int k0 = 0; k0 < K; k0 += 64){
    #pragma unroll
    for (int j = 0; j < 2; j++){ gl_lds16(ag[j], la[j]); gl_lds16(bg[j], lb[j]); }
    #pragma unroll
    for (int j = 0; j < 2; j++){ ag[j] += 64; bg[j] += 64; }
    __syncthreads();
    #pragma unroll
    for (int ph = 0; ph < 2; ph++){
      int l16 = ph * 2 + (qd >> 1);
      int woff = (qd & 1) * 8;
      i64 af[4], bfr[4];
      #pragma unroll
      for (int t = 0; t < 4; t++){
        int rowA = wm + t * 16 + r;
        int rowB = wn + t * 16 + r;
        int swA = ((l16 ^ ((rowA >> 1) & 3)) * 16) + woff;
        int swB = ((l16 ^ ((rowB >> 1) & 3)) * 16) + woff;
        af[t]  = *(const i64*)(As + rowA * 64 + swA);
        bfr[t] = *(const i64*)(Bs + rowB * 64 + swB);
      }
      #pragma unroll
      for (int mt = 0; mt < 4; mt++)
        #pragma unroll
        for (int nt = 0; nt < 4; nt++){
          if (MODE == 5)
            acc[mt][nt] = __builtin_amdgcn_mfma_f32_16x16x32_fp8_fp8(af[mt], bfr[nt], acc[mt][nt], 0, 0, 0);
          else
            acc[mt][nt] = __builtin_amdgcn_mfma_f32_16x16x32_fp8_fp8(bfr[nt], af[mt], acc[mt][nt], 0, 0, 0);
        }
    }
    __syncthreads();
  }

  if (MODE == 2 || MODE == 4){
    const int region = (MODE == 4) ? (n0 >> 8) : 0;
    const float* bb = (MODE == 4) ? (region == 0 ? bq : bk) : bias;
    #pragma unroll
    for (int mt = 0; mt < 4; mt++)
      #pragma unroll
      for (int nt = 0; nt < 4; nt++){
        int ml  = wm + mt * 16 + r;
        int nl0 = wn + nt * 16 + qd * 4;
        int bidx = (MODE == 4) ? ((n0 & 255) + nl0) : (n0 + nl0);
        float v0 = acc[mt][nt][0] + bb[bidx + 0];
        float v1 = acc[mt][nt][1] + bb[bidx + 1];
        float v2 = acc[mt][nt][2] + bb[bidx + 2];
        float v3 = acc[mt][nt][3] + bb[bidx + 3];
        if (MODE == 2){
          v0 = fmaxf(v0, 0.f); v1 = fmaxf(v1, 0.f);
          v2 = fmaxf(v2, 0.f); v3 = fmaxf(v3, 0.f);
        }
        if (MODE == 4 && region == 0){
          v0 *= QSCALE; v1 *= QSCALE; v2 *= QSCALE; v3 *= QSCALE;
        }
        *(unsigned*)(S8 + ml * 136 + nl0) = pack4_fp8(v0, v1, v2, v3);
      }
    __syncthreads();
    int lr = tid >> 1, seg = tid & 1;
    #pragma unroll
    for (int j = 0; j < 4; j++){
      int nl = seg * 64 + j * 16;
      uint2 a = *(uint2*)(S8 + lr * 136 + nl);
      uint2 b = *(uint2*)(S8 + lr * 136 + nl + 8);
      uint4 st = make_uint4(a.x, a.y, b.x, b.y);
      if (MODE == 2){
        *(uint4*)(out8 + (size_t)(m0 + lr) * N + n0 + nl) = st;
      } else {
        int m = m0 + lr;
        int b_ = m / 360, s = m - b_ * 360;
        int nnl = (n0 & 255) + nl;
        int h = nnl >> 6, dk = nnl & 63;
        size_t roff = (region == 1) ? 23592960ull : 0ull;
        *(uint4*)(out8 + roff + ((size_t)(b_ * 4 + h) * 360 + s) * 64 + dk) = st;
      }
    }
  } else if (MODE == 5){
    #pragma unroll
    for (int mt = 0; mt < 4; mt++)
      #pragma unroll
      for (int nt = 0; nt < 4; nt++){
        int nl  = wn + nt * 16 + r;
        int ml0 = wm + mt * 16 + qd * 4;
        float bv_ = bias[n0 + nl];
        *(unsigned*)(S8 + nl * 136 + ml0) =
            pack4_fp8(acc[mt][nt][0] + bv_, acc[mt][nt][1] + bv_,
                      acc[mt][nt][2] + bv_, acc[mt][nt][3] + bv_);
      }
    __syncthreads();
    int nn = tid >> 1, part = tid & 1;
    int nnl = n0 + nn;
    int h = nnl >> 6, dk = nnl & 63;
    #pragma unroll
    for (int j0 = 0; j0 < 64; j0 += 8){
      int mm = m0 + part * 64 + j0;
      int b_ = mm / 360, s = mm - b_ * 360;
      uint2 val = *(uint2*)(S8 + nn * 136 + part * 64 + j0);
      *(uint2*)(out8 + ((size_t)((b_ * 4 + h) * 64 + dk)) * 360 + s) = val;
    }
  } else {  // MODE 3
    #pragma unroll
    for (int half = 0; half < 2; half++){
      if ((wave >> 1) == half){
        #pragma unroll
        for (int mt = 0; mt < 4; mt++)
          #pragma unroll
          for (int nt = 0; nt < 4; nt++){
            int ml  = mt * 16 + r;
            int nl0 = wn + nt * 16 + qd * 4;
            float v0 = acc[mt][nt][0] + bias[n0 + nl0 + 0];
            float v1 = acc[mt][nt][1] + bias[n0 + nl0 + 1];
            float v2 = acc[mt][nt][2] + bias[n0 + nl0 + 2];
            float v3 = acc[mt][nt][3] + bias[n0 + nl0 + 3];
            *(unsigned*)(&Cs[ml][nl0])     = pack2(v0, v1);
            *(unsigned*)(&Cs[ml][nl0 + 2]) = pack2(v2, v3);
          }
      }
      __syncthreads();
      int mbase = m0 + half * 64;
      int lr = tid >> 2, seg = tid & 3;
      bf16* op = xres + (size_t)(mbase + lr) * 256 + n0 + seg * 32;
      #pragma unroll
      for (int j = 0; j < 4; j++){
        uint4 cv = *(uint4*)(&Cs[lr][seg * 32 + j * 8]);
        uint4 xv = *(uint4*)(op + j * 8);
        bf16* ca = (bf16*)&cv; bf16* xa = (bf16*)&xv;
        bf16 o8[8];
        #pragma unroll
        for (int t = 0; t < 8; t++)
          o8[t] = __float2bfloat16(__bfloat162float(ca[t]) + __bfloat162float(xa[t]));
        *(uint4*)(op + j * 8) = *(uint4*)o8;
      }
      __syncthreads();
    }
  }
}

// attn5: fp8 flash attention, exp2 path (q pre-scaled by QSCALE), split kc
// loop, SINGLE Pb + two lgkmcnt waits (R13 structure: keeps VGPR ~64).
__global__ __launch_bounds__(512) void attn5(
    const uchar* __restrict__ q, const uchar* __restrict__ kk, const uchar* __restrict__ vt,
    const int* __restrict__ src, uchar* __restrict__ ctx8)
{
  __shared__ uchar Ks[360][80];
  __shared__ uchar Pb[8][16][48];
  __shared__ uchar Cb[8][16][80];
  int bh = blockIdx.x;
  int b = bh >> 2, h = bh & 3;
  int wave = threadIdx.x >> 6, lane = threadIdx.x & 63;
  int r = lane & 15, qd = lane >> 4;
  const uchar* qb = q  + (size_t)bh * 360 * 64;
  const uchar* kb = kk + (size_t)bh * 360 * 64;
  const uchar* vb = vt + (size_t)bh * 64 * 360;
  const int* srow = src + b * 360;

  for (int c = threadIdx.x; c < 1440; c += 512){
    int row = c >> 2, g = c & 3;
    *(uint4*)(&Ks[row][g * 16]) = *(const uint4*)(kb + row * 64 + g * 16);
  }
  __syncthreads();

  i64 qa0[3], qa1[3];
  float lsum[3];
  f32x4 accO[3][4];
  #pragma unroll
  for (int tl = 0; tl < 3; tl++){
    int qt = wave * 3 + tl;
    int qg = qt * 16 + r;
    int qrow = qg > 359 ? 359 : qg;
    bool qp = (qg < 360) && (srow[qg] == 799);   // PAD query -> zero q: exp2(0)=1 uniform
    qa0[tl] = qp ? 0 : *(const i64*)(qb + qrow * 64 + qd * 8);
    qa1[tl] = qp ? 0 : *(const i64*)(qb + qrow * 64 + 32 + qd * 8);
    lsum[tl] = 0.f;
    #pragma unroll
    for (int dt = 0; dt < 4; dt++) accO[tl][dt] = (f32x4){0.f, 0.f, 0.f, 0.f};
  }

  // ---- main: kc 0..10 (keys < 352: no masks, no clamps) ----
  for (int kc = 0; kc < 11; kc++){
    i64 kf00 = *(const i64*)(&Ks[kc * 32 + r][qd * 8]);
    i64 kf01 = *(const i64*)(&Ks[kc * 32 + r][32 + qd * 8]);
    i64 kf10 = *(const i64*)(&Ks[kc * 32 + 16 + r][qd * 8]);
    i64 kf11 = *(const i64*)(&Ks[kc * 32 + 16 + r][32 + qd * 8]);
    i64 vf[4];
    #pragma unroll
    for (int dt = 0; dt < 4; dt++)
      vf[dt] = *(const i64*)(vb + (size_t)(dt * 16 + r) * 360 + kc * 32 + qd * 8);

    #pragma unroll
    for (int tl = 0; tl < 3; tl++){
      f32x4 z0 = {0.f, 0.f, 0.f, 0.f}, z1 = {0.f, 0.f, 0.f, 0.f};
      z0 = __builtin_amdgcn_mfma_f32_16x16x32_fp8_fp8(kf00, qa0[tl], z0, 0, 0, 0);
      z0 = __builtin_amdgcn_mfma_f32_16x16x32_fp8_fp8(kf01, qa1[tl], z0, 0, 0, 0);
      z1 = __builtin_amdgcn_mfma_f32_16x16x32_fp8_fp8(kf10, qa0[tl], z1, 0, 0, 0);
      z1 = __builtin_amdgcn_mfma_f32_16x16x32_fp8_fp8(kf11, qa1[tl], z1, 0, 0, 0);
      float p0[4], p1[4];
      #pragma unroll
      for (int i = 0; i < 4; i++){
        p0[i] = exp2f(z0[i]);
        p1[i] = exp2f(z1[i]);
        lsum[tl] += p0[i] + p1[i];
      }
      *(unsigned*)(&Pb[wave][r][qd * 4])      = pack4_fp8(p0[0], p0[1], p0[2], p0[3]);
      *(unsigned*)(&Pb[wave][r][16 + qd * 4]) = pack4_fp8(p1[0], p1[1], p1[2], p1[3]);
      asm volatile("s_waitcnt lgkmcnt(0)" ::: "memory");
      i64 pa = *(const i64*)(&Pb[wave][r][qd * 8]);
      #pragma unroll
      for (int dt = 0; dt < 4; dt++)
        accO[tl][dt] = __builtin_amdgcn_mfma_f32_16x16x32_fp8_fp8(pa, vf[dt], accO[tl][dt], 0, 0, 0);
      asm volatile("s_waitcnt lgkmcnt(0)" ::: "memory");  // WAR before next step's P writes
    }
  }
  // ---- tail: kc = 11 (keys 352..383; mask >=360) ----
  {
    int krow0 = 352 + r;
    if (krow0 > 359) krow0 = 359;
    i64 kf00 = *(const i64*)(&Ks[krow0][qd * 8]);
    i64 kf01 = *(const i64*)(&Ks[krow0][32 + qd * 8]);
    i64 vf[4];
    #pragma unroll
    for (int dt = 0; dt < 4; dt++)
      vf[dt] = *(const i64*)(vb + (size_t)(dt * 16 + r) * 360 + 352 + qd * 8);

    #pragma unroll
    for (int tl = 0; tl < 3; tl++){
      f32x4 z0 = {0.f, 0.f, 0.f, 0.f};
      z0 = __builtin_amdgcn_mfma_f32_16x16x32_fp8_fp8(kf00, qa0[tl], z0, 0, 0, 0);
      z0 = __builtin_amdgcn_mfma_f32_16x16x32_fp8_fp8(kf01, qa1[tl], z0, 0, 0, 0);
      float p0[4];
      #pragma unroll
      for (int i = 0; i < 4; i++){
        int key = 352 + qd * 4 + i;
        p0[i] = (key < 360) ? exp2f(z0[i]) : 0.0f;
        lsum[tl] += p0[i];
      }
      *(unsigned*)(&Pb[wave][r][qd * 4])      = pack4_fp8(p0[0], p0[1], p0[2], p0[3]);
      *(unsigned*)(&Pb[wave][r][16 + qd * 4]) = 0u;
      asm volatile("s_waitcnt lgkmcnt(0)" ::: "memory");
      i64 pa = *(const i64*)(&Pb[wave][r][qd * 8]);
      #pragma unroll
      for (int dt = 0; dt < 4; dt++)
        accO[tl][dt] = __builtin_amdgcn_mfma_f32_16x16x32_fp8_fp8(pa, vf[dt], accO[tl][dt], 0, 0, 0);
      asm volatile("s_waitcnt lgkmcnt(0)" ::: "memory");
    }
  }

  #pragma unroll
  for (int tl = 0; tl < 3; tl++){
    int qt = wave * 3 + tl;
    float ls = lsum[tl];
    ls += __shfl_xor(ls, 16, 64);
    ls += __shfl_xor(ls, 32, 64);
    float invl = 1.0f / ls;
    #pragma unroll
    for (int i = 0; i < 4; i++){
      float inv_i = __shfl(invl, qd * 4 + i, 64);
      #pragma unroll
      for (int dt = 0; dt < 4; dt++)
        Cb[wave][qd * 4 + i][dt * 16 + r] = f2f8(accO[tl][dt][i] * inv_i);
    }
    asm volatile("s_waitcnt lgkmcnt(0)" ::: "memory");
    int qglob = qt * 16 + r;
    if (qglob < 360)
      *(uint4*)(ctx8 + ((size_t)(b * 360 + qglob)) * 256 + h * 64 + qd * 16) =
          *(uint4*)(&Cb[wave][r][qd * 16]);
    asm volatile("s_waitcnt lgkmcnt(0)" ::: "memory");
  }
}

// head: one block per batch (grid 256, 4 waves).
__global__ __launch_bounds__(256) void head_k(
    const bf16* __restrict__ x, const int* __restrict__ src,
    const float* __restrict__ wl, const float* __restrict__ bl,
    float* __restrict__ out)
{
  __shared__ bf16 Xs[192][264];
  int b = blockIdx.x;
  int tid = threadIdx.x;
  int wave = tid >> 6, lane = tid & 63;
  int g = lane >> 3, sub = lane & 7;

  const bf16* xb = x + (size_t)b * 360 * 256;
  for (int it = 0; it < 24; it++){
    int idx = tid + it * 256;
    int row = idx >> 5, col = idx & 31;
    *(uint4*)(&Xs[row][col * 8]) = *(const uint4*)(xb + row * 256 + col * 8);
  }

  float wv[96];
  {
    const float4* wr4 = (const float4*)(wl + (size_t)(g * 256 + sub * 32) * 3);
    #pragma unroll
    for (int c = 0; c < 24; c++) *(float4*)(&wv[c * 4]) = wr4[c];
  }
  float bl0 = bl[0], bl1 = bl[1], bl2 = bl[2];
  const int* sr = src + b * 360;
  __syncthreads();

  for (int p = wave; p < 91; p += 4){
    int i = 0, rem = p;
    while (rem >= 13 - i){ rem -= 13 - i; i++; }
    int j = i + 1 + rem;
    int base = 12 * i - (i * (i - 1)) / 2;
    int pe = base + (j - i) - 1;
    int eb = 28 + 2 * pe;

    int idxg;
    if (g == 0) idxg = 2 * i;
    else if (g == 1) idxg = 2 * i + 1;
    else if (g == 2) idxg = 2 * j;
    else if (g == 3) idxg = 2 * j + 1;
    else idxg = eb + (g - 4);
    bool zm = !(g >= 4 && j == 13);

    uint4 xv[4];
    #pragma unroll
    for (int c = 0; c < 4; c++) xv[c] = *(uint4*)(&Xs[idxg][sub * 32 + c * 8]);
    const bf16* xa = (const bf16*)xv;
    float a0 = 0.f, a1 = 0.f, a2 = 0.f;
    #pragma unroll
    for (int t = 0; t < 32; t++){
      float f = zm ? __bfloat162float(xa[t]) : 0.0f;
      a0 += f * wv[t * 3 + 0];
      a1 += f * wv[t * 3 + 1];
      a2 += f * wv[t * 3 + 2];
    }
    #pragma unroll
    for (int o = 1; o < 64; o <<= 1){
      a0 += __shfl_xor(a0, o, 64);
      a1 += __shfl_xor(a1, o, 64);
      a2 += __shfl_xor(a2, o, 64);
    }
    if (lane == 0){
      int ti = sr[2 * i], ai = sr[2 * i + 1], tj = sr[2 * j], aj = sr[2 * j + 1];
      bool c1 = (ai == 2) || (aj == 2);
      bool c2 = (tj == 1) || (ai == 1) || (aj == 1);
      bool c3 = (ti == 799) || (tj == 799) || (ai == 0) || (aj == 0);
      bool c4 = false;
      if (j < 13){
        int es = 28 + 4 * pe;
        c4 = (sr[es] == 1) || (sr[es + 1] == 1) || (sr[es + 2] == 1) || (sr[es + 3] == 1);
      }
      bool m1 = c3 || c4, m2 = m1 || c2, m3 = m2 || c1;
      float* op = out + ((size_t)b * 91 + p) * 3;
      op[0] = m1 ? -1.0e9f : (a0 + bl0);
      op[1] = m2 ? -1.0e9f : (a1 + bl1);
      op[2] = m3 ? -1.0e9f : (a2 + bl2);
    }
  }
}

extern "C" void kernel_launch(void* const* d_in, const int* in_sizes, int n_in,
                              void* d_out, int out_size, void* d_ws, size_t ws_size,
                              hipStream_t stream)
{
  const int*   src = (const int*)  d_in[0];
  const float* emb = (const float*)d_in[1];
  const float* wq  = (const float*)d_in[2];  const float* bq = (const float*)d_in[3];
  const float* wk  = (const float*)d_in[4];  const float* bk = (const float*)d_in[5];
  const float* wv  = (const float*)d_in[6];  const float* bv = (const float*)d_in[7];
  const float* wo  = (const float*)d_in[8];  const float* bo = (const float*)d_in[9];
  const float* n1a = (const float*)d_in[10]; const float* n1b = (const float*)d_in[11];
  const float* n2a = (const float*)d_in[12]; const float* n2b = (const float*)d_in[13];
  const float* w1  = (const float*)d_in[14]; const float* b1 = (const float*)d_in[15];
  const float* w2  = (const float*)d_in[16]; const float* b2 = (const float*)d_in[17];
  const float* wl  = (const float*)d_in[18]; const float* bl = (const float*)d_in[19];
  float* out = (float*)d_out;

  if (ws_size < 191365120ull) return;

  char* ws = (char*)d_ws;
  bf16*  x    = (bf16*)(ws);
  uchar* xn8  = (uchar*)(ws + 47185920ull);
  char*  R    = ws + 70778880ull;
  uchar* q8   = (uchar*)(R);
  uchar* vt8  = (uchar*)(R + 47185920ull);
  uchar* h8   = (uchar*)(R);
  char*  wC   = ws + 141557760ull;
  uchar* wqkv8 = (uchar*)(wC);
  uchar* wo8   = (uchar*)(wC + 196608);
  uchar* w1f8T = (uchar*)(wC + 262144);
  uchar* w2f8T = (uchar*)(wC + 786432);

  cvt_all<<<1280, 256, 0, stream>>>(wq, wk, wv, wo, w1, w2,
                                    wqkv8, wqkv8 + 65536, wqkv8 + 131072,
                                    wo8, w1f8T, w2f8T);

  embed_ln1<<<23040, 256, 0, stream>>>(src, emb, n1a, n1b, x, xn8);

  gemm_f8<4><<<2880, 256, 0, stream>>>(xn8, 256, wqkv8, 256, nullptr, q8, nullptr,
                                       512, 256, 4, bq, bk);
  gemm_f8<5><<<1440, 256, 0, stream>>>(xn8, 256, wqkv8 + 131072, 256, bv, vt8, nullptr,
                                       256, 256, 2, nullptr, nullptr);

  attn5<<<1024, 512, 0, stream>>>(q8, q8 + 23592960ull, vt8, src, xn8 /* ctx8 */);

  gemm_f8<3><<<1440, 256, 0, stream>>>(xn8, 256, wo8, 256, bo, nullptr, x,
                                       256, 256, 2, nullptr, nullptr);

  ln_k8<<<23040, 256, 0, stream>>>(x, n2a, n2b, xn8);

  for (int mc = 0; mc < 4; mc++){
    const uchar* xnc = xn8 + (size_t)mc * 23040 * 256;
    bf16* xc = x + (size_t)mc * 23040 * 256;
    gemm_f8<2><<<2880, 256, 0, stream>>>(xnc, 256, w1f8T, 256, b1, h8, nullptr,
                                         2048, 256, 16, nullptr, nullptr);
    gemm_f8<3><<<360, 256, 0, stream>>>(h8, 2048, w2f8T, 2048, b2, nullptr, xc,
                                        256, 2048, 2, nullptr, nullptr);
  }

  head_k<<<256, 256, 0, stream>>>(x, src, wl, bl, out);
}

// Round 17
// 684.696 us; speedup vs baseline: 1.0562x; 1.0537x over previous
//
#include <hip/hip_runtime.h>
#include <hip/hip_bf16.h>
#include <math.h>

// ---------------------------------------------------------------------------
// Round 16: stop the attn5 spill at its actual source. R15/R16 showed VGPR
// 128 + 55MB scratch WRITE regardless of wait structure -> the R15 "double
// buffer" theory was wrong. Real cause: split kc loop has clean affine
// addresses and trip count 11 -> LLVM fully unrolls, hoists K/V loads across
// iterations, explodes live ranges. Fix: #pragma unroll 1 on the kc loop.
// All else = R16 (exp2/QSCALE fold, pad-q zeroing, split tail, single Pb).
// ws guard 191,365,120 B unchanged.
// ---------------------------------------------------------------------------

using bf16 = __hip_bfloat16;
typedef __attribute__((ext_vector_type(4))) float f32x4;
typedef long long i64;
typedef unsigned char uchar;

#define QSCALE 0.18033688011112042f   // 0.125 * log2(e)

static __device__ __forceinline__ float wave_sum64(float v){
  #pragma unroll
  for (int o = 32; o >= 1; o >>= 1) v += __shfl_xor(v, o, 64);
  return v;
}

static __device__ __forceinline__ void gl_lds16(const void* g, void* l){
  __builtin_amdgcn_global_load_lds((const __attribute__((address_space(1))) void*)g,
                                   (__attribute__((address_space(3))) void*)l, 16, 0, 0);
}

static __device__ __forceinline__ unsigned pack2(float a, float b){
  union { bf16 h[2]; unsigned u; } u;
  u.h[0] = __float2bfloat16(a); u.h[1] = __float2bfloat16(b);
  return u.u;
}

static __device__ __forceinline__ uchar f2f8(float v){
  return (uchar)(__builtin_amdgcn_cvt_pk_fp8_f32(v, 0.f, 0, false) & 0xff);
}
static __device__ __forceinline__ unsigned pack4_fp8(float a, float b, float c, float d){
  int v = __builtin_amdgcn_cvt_pk_fp8_f32(a, b, 0, false);
  v = __builtin_amdgcn_cvt_pk_fp8_f32(c, d, v, true);
  return (unsigned)v;
}

// merged weight prep: all 6 jobs fp8 transposed. 1280 blocks.
__global__ __launch_bounds__(256) void cvt_all(
    const float* s0, const float* s1, const float* s2, const float* s3,
    const float* s4, const float* s5,
    uchar* d0, uchar* d1, uchar* d2, uchar* d3, uchar* d4, uchar* d5)
{
  __shared__ float t[32][33];
  const float* srcs[6] = {s0, s1, s2, s3, s4, s5};
  uchar* dsts[6] = {d0, d1, d2, d3, d4, d5};
  const int Ks[6] = {256, 256, 256, 256, 256, 2048};
  const int Ns[6] = {256, 256, 256, 256, 2048, 256};
  const int offs[7] = {0, 64, 128, 192, 256, 768, 1280};
  int bid = blockIdx.x, j = 5;
  #pragma unroll
  for (int q = 4; q >= 0; q--) if (bid < offs[q + 1]) j = q;
  int local = bid - offs[j];
  int K = Ks[j], N = Ns[j];
  const float* src = srcs[j];
  uchar* dst = dsts[j];
  int kt = K >> 5;
  int kb = (local % kt) * 32, nb = (local / kt) * 32;
  int tx = threadIdx.x & 31, ty = threadIdx.x >> 5;
  #pragma unroll
  for (int dy = 0; dy < 32; dy += 8)
    t[ty + dy][tx] = src[(size_t)(kb + ty + dy) * N + nb + tx];
  __syncthreads();
  #pragma unroll
  for (int dy = 0; dy < 32; dy += 8)
    dst[(size_t)(nb + ty + dy) * K + kb + tx] = f2f8(t[tx][ty + dy]);
}

// embed + PE + scale -> x (bf16), LN1 -> fp8 xn8. one wave/row, grid 23040.
__global__ __launch_bounds__(256) void embed_ln1(
    const int* __restrict__ src, const float* __restrict__ emb,
    const float* __restrict__ na, const float* __restrict__ nb,
    bf16* __restrict__ x, uchar* __restrict__ xn8)
{
  int row  = blockIdx.x * 4 + (threadIdx.x >> 6);
  int lane = threadIdx.x & 63;
  int s = row % 360;
  int tok = src[row];
  float4 v = *(const float4*)(emb + (size_t)tok * 256 + lane * 4);
  float vv[4] = {v.x, v.y, v.z, v.w};
  if (s < 340){
    const float C = (-2.0f / 256.0f) * 13.287712379549449f;
    #pragma unroll
    for (int t = 0; t < 4; t++){
      int c = lane * 4 + t;
      float ang = (float)s * exp2f(C * (float)c);
      float pe = (c & 1) ? cosf(ang) : sinf(ang);
      vv[t] = 16.0f * vv[t] + pe;
    }
  }
  float sum = wave_sum64(vv[0] + vv[1] + vv[2] + vv[3]);
  float mu = sum * (1.0f / 256.0f);
  float d0 = vv[0]-mu, d1 = vv[1]-mu, d2 = vv[2]-mu, d3 = vv[3]-mu;
  float sq = wave_sum64(d0*d0 + d1*d1 + d2*d2 + d3*d3);
  float inv = 1.0f / (sqrtf(sq * (1.0f / 255.0f)) + 1e-6f);
  bf16 xo[4] = { __float2bfloat16(vv[0]), __float2bfloat16(vv[1]),
                 __float2bfloat16(vv[2]), __float2bfloat16(vv[3]) };
  *(uint2*)(x + (size_t)row * 256 + lane * 4) = *(uint2*)xo;
  float4 a4 = *(const float4*)(na + lane * 4);
  float4 b4 = *(const float4*)(nb + lane * 4);
  unsigned u = pack4_fp8(a4.x * d0 * inv + b4.x, a4.y * d1 * inv + b4.y,
                         a4.z * d2 * inv + b4.z, a4.w * d3 * inv + b4.w);
  *(unsigned*)(xn8 + (size_t)row * 256 + lane * 4) = u;
}

// LN2 over bf16 x -> fp8 xn8. one wave per row. grid 23040.
__global__ __launch_bounds__(256) void ln_k8(
    const bf16* __restrict__ x, const float* __restrict__ na,
    const float* __restrict__ nb, uchar* __restrict__ xn8)
{
  int row  = blockIdx.x * 4 + (threadIdx.x >> 6);
  int lane = threadIdx.x & 63;
  uint2 raw = *(const uint2*)(x + (size_t)row * 256 + lane * 4);
  bf16* xr = (bf16*)&raw;
  float v0 = __bfloat162float(xr[0]), v1 = __bfloat162float(xr[1]);
  float v2 = __bfloat162float(xr[2]), v3 = __bfloat162float(xr[3]);
  float sum = wave_sum64(v0 + v1 + v2 + v3);
  float mu = sum * (1.0f / 256.0f);
  float d0 = v0-mu, d1 = v1-mu, d2 = v2-mu, d3 = v3-mu;
  float sq = wave_sum64(d0*d0 + d1*d1 + d2*d2 + d3*d3);
  float inv = 1.0f / (sqrtf(sq * (1.0f / 255.0f)) + 1e-6f);
  float4 a4 = *(const float4*)(na + lane * 4);
  float4 b4 = *(const float4*)(nb + lane * 4);
  unsigned u = pack4_fp8(a4.x * d0 * inv + b4.x, a4.y * d1 * inv + b4.y,
                         a4.z * d2 * inv + b4.z, a4.w * d3 * inv + b4.w);
  *(unsigned*)(xn8 + (size_t)row * 256 + lane * 4) = u;
}

// fp8 GEMM, modes as R13. MODE4 region 0 (q) scaled by QSCALE.
template<int MODE>
__global__ __launch_bounds__(256) void gemm_f8(
    const uchar* __restrict__ A, int lda,
    const uchar* __restrict__ Bt, int ldb,
    const float* __restrict__ bias,
    uchar* __restrict__ out8, bf16* __restrict__ xres,
    int N, int K, int nTiles,
    const float* __restrict__ bq, const float* __restrict__ bk)
{
  __shared__ __align__(16) char smem[17408];
  uchar* As = (uchar*)smem;
  uchar* Bs = (uchar*)(smem + 8192);
  uchar* S8 = (uchar*)smem;
  bf16 (*Cs)[136] = (bf16 (*)[136])smem;
  int chunk = gridDim.x >> 3;
  int bi = (blockIdx.x & 7) * chunk + (blockIdx.x >> 3);
  int m0 = (bi / nTiles) * 128, n0 = (bi % nTiles) * 128;
  int tid = threadIdx.x;
  int wave = tid >> 6, lane = tid & 63;
  int wm = (wave >> 1) * 64, wn = (wave & 1) * 64;
  int r = lane & 15, qd = lane >> 4;

  const uchar* ag[2]; const uchar* bg[2]; uchar* la[2]; uchar* lb[2];
  #pragma unroll
  for (int j = 0; j < 2; j++){
    int c = tid + j * 256;
    int row = c >> 2, pp = c & 3;
    int lco = pp ^ ((row >> 1) & 3);
    ag[j] = A  + (size_t)(m0 + row) * lda + lco * 16;
    bg[j] = Bt + (size_t)(n0 + row) * ldb + lco * 16;
    la[j] = As + (size_t)c * 16;
    lb[j] = Bs + (size_t)c * 16;
  }

  f32x4 acc[4][4];
  #pragma unroll
  for (int mt = 0; mt < 4; mt++)
    #pragma unroll
    for (int nt = 0; nt < 4; nt++) acc[mt][nt] = (f32x4){0.f, 0.f, 0.f, 0.f};

  for (int k0 = 0; k0 < K; k0 += 64){
    #pragma unroll
    for (int j = 0; j < 2; j++){ gl_lds16(ag[j], la[j]); gl_lds16(bg[j], lb[j]); }
    #pragma unroll
    for (int j = 0; j < 2; j++){ ag[j] += 64; bg[j] += 64; }
    __syncthreads();
    #pragma unroll
    for (int ph = 0; ph < 2; ph++){
      int l16 = ph * 2 + (qd >> 1);
      int woff = (qd & 1) * 8;
      i64 af[4], bfr[4];
      #pragma unroll
      for (int t = 0; t < 4; t++){
        int rowA = wm + t * 16 + r;
        int rowB = wn + t * 16 + r;
        int swA = ((l16 ^ ((rowA >> 1) & 3)) * 16) + woff;
        int swB = ((l16 ^ ((rowB >> 1) & 3)) * 16) + woff;
        af[t]  = *(const i64*)(As + rowA * 64 + swA);
        bfr[t] = *(const i64*)(Bs + rowB * 64 + swB);
      }
      #pragma unroll
      for (int mt = 0; mt < 4; mt++)
        #pragma unroll
        for (int nt = 0; nt < 4; nt++){
          if (MODE == 5)
            acc[mt][nt] = __builtin_amdgcn_mfma_f32_16x16x32_fp8_fp8(af[mt], bfr[nt], acc[mt][nt], 0, 0, 0);
          else
            acc[mt][nt] = __builtin_amdgcn_mfma_f32_16x16x32_fp8_fp8(bfr[nt], af[mt], acc[mt][nt], 0, 0, 0);
        }
    }
    __syncthreads();
  }

  if (MODE == 2 || MODE == 4){
    const int region = (MODE == 4) ? (n0 >> 8) : 0;
    const float* bb = (MODE == 4) ? (region == 0 ? bq : bk) : bias;
    #pragma unroll
    for (int mt = 0; mt < 4; mt++)
      #pragma unroll
      for (int nt = 0; nt < 4; nt++){
        int ml  = wm + mt * 16 + r;
        int nl0 = wn + nt * 16 + qd * 4;
        int bidx = (MODE == 4) ? ((n0 & 255) + nl0) : (n0 + nl0);
        float v0 = acc[mt][nt][0] + bb[bidx + 0];
        float v1 = acc[mt][nt][1] + bb[bidx + 1];
        float v2 = acc[mt][nt][2] + bb[bidx + 2];
        float v3 = acc[mt][nt][3] + bb[bidx + 3];
        if (MODE == 2){
          v0 = fmaxf(v0, 0.f); v1 = fmaxf(v1, 0.f);
          v2 = fmaxf(v2, 0.f); v3 = fmaxf(v3, 0.f);
        }
        if (MODE == 4 && region == 0){
          v0 *= QSCALE; v1 *= QSCALE; v2 *= QSCALE; v3 *= QSCALE;
        }
        *(unsigned*)(S8 + ml * 136 + nl0) = pack4_fp8(v0, v1, v2, v3);
      }
    __syncthreads();
    int lr = tid >> 1, seg = tid & 1;
    #pragma unroll
    for (int j = 0; j < 4; j++){
      int nl = seg * 64 + j * 16;
      uint2 a = *(uint2*)(S8 + lr * 136 + nl);
      uint2 b = *(uint2*)(S8 + lr * 136 + nl + 8);
      uint4 st = make_uint4(a.x, a.y, b.x, b.y);
      if (MODE == 2){
        *(uint4*)(out8 + (size_t)(m0 + lr) * N + n0 + nl) = st;
      } else {
        int m = m0 + lr;
        int b_ = m / 360, s = m - b_ * 360;
        int nnl = (n0 & 255) + nl;
        int h = nnl >> 6, dk = nnl & 63;
        size_t roff = (region == 1) ? 23592960ull : 0ull;
        *(uint4*)(out8 + roff + ((size_t)(b_ * 4 + h) * 360 + s) * 64 + dk) = st;
      }
    }
  } else if (MODE == 5){
    #pragma unroll
    for (int mt = 0; mt < 4; mt++)
      #pragma unroll
      for (int nt = 0; nt < 4; nt++){
        int nl  = wn + nt * 16 + r;
        int ml0 = wm + mt * 16 + qd * 4;
        float bv_ = bias[n0 + nl];
        *(unsigned*)(S8 + nl * 136 + ml0) =
            pack4_fp8(acc[mt][nt][0] + bv_, acc[mt][nt][1] + bv_,
                      acc[mt][nt][2] + bv_, acc[mt][nt][3] + bv_);
      }
    __syncthreads();
    int nn = tid >> 1, part = tid & 1;
    int nnl = n0 + nn;
    int h = nnl >> 6, dk = nnl & 63;
    #pragma unroll
    for (int j0 = 0; j0 < 64; j0 += 8){
      int mm = m0 + part * 64 + j0;
      int b_ = mm / 360, s = mm - b_ * 360;
      uint2 val = *(uint2*)(S8 + nn * 136 + part * 64 + j0);
      *(uint2*)(out8 + ((size_t)((b_ * 4 + h) * 64 + dk)) * 360 + s) = val;
    }
  } else {  // MODE 3
    #pragma unroll
    for (int half = 0; half < 2; half++){
      if ((wave >> 1) == half){
        #pragma unroll
        for (int mt = 0; mt < 4; mt++)
          #pragma unroll
          for (int nt = 0; nt < 4; nt++){
            int ml  = mt * 16 + r;
            int nl0 = wn + nt * 16 + qd * 4;
            float v0 = acc[mt][nt][0] + bias[n0 + nl0 + 0];
            float v1 = acc[mt][nt][1] + bias[n0 + nl0 + 1];
            float v2 = acc[mt][nt][2] + bias[n0 + nl0 + 2];
            float v3 = acc[mt][nt][3] + bias[n0 + nl0 + 3];
            *(unsigned*)(&Cs[ml][nl0])     = pack2(v0, v1);
            *(unsigned*)(&Cs[ml][nl0 + 2]) = pack2(v2, v3);
          }
      }
      __syncthreads();
      int mbase = m0 + half * 64;
      int lr = tid >> 2, seg = tid & 3;
      bf16* op = xres + (size_t)(mbase + lr) * 256 + n0 + seg * 32;
      #pragma unroll
      for (int j = 0; j < 4; j++){
        uint4 cv = *(uint4*)(&Cs[lr][seg * 32 + j * 8]);
        uint4 xv = *(uint4*)(op + j * 8);
        bf16* ca = (bf16*)&cv; bf16* xa = (bf16*)&xv;
        bf16 o8[8];
        #pragma unroll
        for (int t = 0; t < 8; t++)
          o8[t] = __float2bfloat16(__bfloat162float(ca[t]) + __bfloat162float(xa[t]));
        *(uint4*)(op + j * 8) = *(uint4*)o8;
      }
      __syncthreads();
    }
  }
}

// attn5: fp8 flash attention, exp2 path, split kc loop with NO UNROLL on the
// main loop (R16 spill fix), single Pb + two lgkmcnt waits.
__global__ __launch_bounds__(512) void attn5(
    const uchar* __restrict__ q, const uchar* __restrict__ kk, const uchar* __restrict__ vt,
    const int* __restrict__ src, uchar* __restrict__ ctx8)
{
  __shared__ uchar Ks[360][80];
  __shared__ uchar Pb[8][16][48];
  __shared__ uchar Cb[8][16][80];
  int bh = blockIdx.x;
  int b = bh >> 2, h = bh & 3;
  int wave = threadIdx.x >> 6, lane = threadIdx.x & 63;
  int r = lane & 15, qd = lane >> 4;
  const uchar* qb = q  + (size_t)bh * 360 * 64;
  const uchar* kb = kk + (size_t)bh * 360 * 64;
  const uchar* vb = vt + (size_t)bh * 64 * 360;
  const int* srow = src + b * 360;

  for (int c = threadIdx.x; c < 1440; c += 512){
    int row = c >> 2, g = c & 3;
    *(uint4*)(&Ks[row][g * 16]) = *(const uint4*)(kb + row * 64 + g * 16);
  }
  __syncthreads();

  i64 qa0[3], qa1[3];
  float lsum[3];
  f32x4 accO[3][4];
  #pragma unroll
  for (int tl = 0; tl < 3; tl++){
    int qt = wave * 3 + tl;
    int qg = qt * 16 + r;
    int qrow = qg > 359 ? 359 : qg;
    bool qp = (qg < 360) && (srow[qg] == 799);   // PAD query -> zero q: exp2(0)=1 uniform
    qa0[tl] = qp ? 0 : *(const i64*)(qb + qrow * 64 + qd * 8);
    qa1[tl] = qp ? 0 : *(const i64*)(qb + qrow * 64 + 32 + qd * 8);
    lsum[tl] = 0.f;
    #pragma unroll
    for (int dt = 0; dt < 4; dt++) accO[tl][dt] = (f32x4){0.f, 0.f, 0.f, 0.f};
  }

  // ---- main: kc 0..10 (no masks). unroll 1: keep live ranges to one iter ----
  #pragma unroll 1
  for (int kc = 0; kc < 11; kc++){
    i64 kf00 = *(const i64*)(&Ks[kc * 32 + r][qd * 8]);
    i64 kf01 = *(const i64*)(&Ks[kc * 32 + r][32 + qd * 8]);
    i64 kf10 = *(const i64*)(&Ks[kc * 32 + 16 + r][qd * 8]);
    i64 kf11 = *(const i64*)(&Ks[kc * 32 + 16 + r][32 + qd * 8]);
    i64 vf[4];
    #pragma unroll
    for (int dt = 0; dt < 4; dt++)
      vf[dt] = *(const i64*)(vb + (size_t)(dt * 16 + r) * 360 + kc * 32 + qd * 8);

    #pragma unroll
    for (int tl = 0; tl < 3; tl++){
      f32x4 z0 = {0.f, 0.f, 0.f, 0.f}, z1 = {0.f, 0.f, 0.f, 0.f};
      z0 = __builtin_amdgcn_mfma_f32_16x16x32_fp8_fp8(kf00, qa0[tl], z0, 0, 0, 0);
      z0 = __builtin_amdgcn_mfma_f32_16x16x32_fp8_fp8(kf01, qa1[tl], z0, 0, 0, 0);
      z1 = __builtin_amdgcn_mfma_f32_16x16x32_fp8_fp8(kf10, qa0[tl], z1, 0, 0, 0);
      z1 = __builtin_amdgcn_mfma_f32_16x16x32_fp8_fp8(kf11, qa1[tl], z1, 0, 0, 0);
      float p0[4], p1[4];
      #pragma unroll
      for (int i = 0; i < 4; i++){
        p0[i] = exp2f(z0[i]);
        p1[i] = exp2f(z1[i]);
        lsum[tl] += p0[i] + p1[i];
      }
      *(unsigned*)(&Pb[wave][r][qd * 4])      = pack4_fp8(p0[0], p0[1], p0[2], p0[3]);
      *(unsigned*)(&Pb[wave][r][16 + qd * 4]) = pack4_fp8(p1[0], p1[1], p1[2], p1[3]);
      asm volatile("s_waitcnt lgkmcnt(0)" ::: "memory");
      i64 pa = *(const i64*)(&Pb[wave][r][qd * 8]);
      #pragma unroll
      for (int dt = 0; dt < 4; dt++)
        accO[tl][dt] = __builtin_amdgcn_mfma_f32_16x16x32_fp8_fp8(pa, vf[dt], accO[tl][dt], 0, 0, 0);
      asm volatile("s_waitcnt lgkmcnt(0)" ::: "memory");  // WAR before next step's P writes
    }
  }
  // ---- tail: kc = 11 (keys 352..383; mask >=360) ----
  {
    int krow0 = 352 + r;
    if (krow0 > 359) krow0 = 359;
    i64 kf00 = *(const i64*)(&Ks[krow0][qd * 8]);
    i64 kf01 = *(const i64*)(&Ks[krow0][32 + qd * 8]);
    i64 vf[4];
    #pragma unroll
    for (int dt = 0; dt < 4; dt++)
      vf[dt] = *(const i64*)(vb + (size_t)(dt * 16 + r) * 360 + 352 + qd * 8);

    #pragma unroll
    for (int tl = 0; tl < 3; tl++){
      f32x4 z0 = {0.f, 0.f, 0.f, 0.f};
      z0 = __builtin_amdgcn_mfma_f32_16x16x32_fp8_fp8(kf00, qa0[tl], z0, 0, 0, 0);
      z0 = __builtin_amdgcn_mfma_f32_16x16x32_fp8_fp8(kf01, qa1[tl], z0, 0, 0, 0);
      float p0[4];
      #pragma unroll
      for (int i = 0; i < 4; i++){
        int key = 352 + qd * 4 + i;
        p0[i] = (key < 360) ? exp2f(z0[i]) : 0.0f;
        lsum[tl] += p0[i];
      }
      *(unsigned*)(&Pb[wave][r][qd * 4])      = pack4_fp8(p0[0], p0[1], p0[2], p0[3]);
      *(unsigned*)(&Pb[wave][r][16 + qd * 4]) = 0u;
      asm volatile("s_waitcnt lgkmcnt(0)" ::: "memory");
      i64 pa = *(const i64*)(&Pb[wave][r][qd * 8]);
      #pragma unroll
      for (int dt = 0; dt < 4; dt++)
        accO[tl][dt] = __builtin_amdgcn_mfma_f32_16x16x32_fp8_fp8(pa, vf[dt], accO[tl][dt], 0, 0, 0);
      asm volatile("s_waitcnt lgkmcnt(0)" ::: "memory");
    }
  }

  #pragma unroll
  for (int tl = 0; tl < 3; tl++){
    int qt = wave * 3 + tl;
    float ls = lsum[tl];
    ls += __shfl_xor(ls, 16, 64);
    ls += __shfl_xor(ls, 32, 64);
    float invl = 1.0f / ls;
    #pragma unroll
    for (int i = 0; i < 4; i++){
      float inv_i = __shfl(invl, qd * 4 + i, 64);
      #pragma unroll
      for (int dt = 0; dt < 4; dt++)
        Cb[wave][qd * 4 + i][dt * 16 + r] = f2f8(accO[tl][dt][i] * inv_i);
    }
    asm volatile("s_waitcnt lgkmcnt(0)" ::: "memory");
    int qglob = qt * 16 + r;
    if (qglob < 360)
      *(uint4*)(ctx8 + ((size_t)(b * 360 + qglob)) * 256 + h * 64 + qd * 16) =
          *(uint4*)(&Cb[wave][r][qd * 16]);
    asm volatile("s_waitcnt lgkmcnt(0)" ::: "memory");
  }
}

// head: one block per batch (grid 256, 4 waves).
__global__ __launch_bounds__(256) void head_k(
    const bf16* __restrict__ x, const int* __restrict__ src,
    const float* __restrict__ wl, const float* __restrict__ bl,
    float* __restrict__ out)
{
  __shared__ bf16 Xs[192][264];
  int b = blockIdx.x;
  int tid = threadIdx.x;
  int wave = tid >> 6, lane = tid & 63;
  int g = lane >> 3, sub = lane & 7;

  const bf16* xb = x + (size_t)b * 360 * 256;
  for (int it = 0; it < 24; it++){
    int idx = tid + it * 256;
    int row = idx >> 5, col = idx & 31;
    *(uint4*)(&Xs[row][col * 8]) = *(const uint4*)(xb + row * 256 + col * 8);
  }

  float wv[96];
  {
    const float4* wr4 = (const float4*)(wl + (size_t)(g * 256 + sub * 32) * 3);
    #pragma unroll
    for (int c = 0; c < 24; c++) *(float4*)(&wv[c * 4]) = wr4[c];
  }
  float bl0 = bl[0], bl1 = bl[1], bl2 = bl[2];
  const int* sr = src + b * 360;
  __syncthreads();

  for (int p = wave; p < 91; p += 4){
    int i = 0, rem = p;
    while (rem >= 13 - i){ rem -= 13 - i; i++; }
    int j = i + 1 + rem;
    int base = 12 * i - (i * (i - 1)) / 2;
    int pe = base + (j - i) - 1;
    int eb = 28 + 2 * pe;

    int idxg;
    if (g == 0) idxg = 2 * i;
    else if (g == 1) idxg = 2 * i + 1;
    else if (g == 2) idxg = 2 * j;
    else if (g == 3) idxg = 2 * j + 1;
    else idxg = eb + (g - 4);
    bool zm = !(g >= 4 && j == 13);

    uint4 xv[4];
    #pragma unroll
    for (int c = 0; c < 4; c++) xv[c] = *(uint4*)(&Xs[idxg][sub * 32 + c * 8]);
    const bf16* xa = (const bf16*)xv;
    float a0 = 0.f, a1 = 0.f, a2 = 0.f;
    #pragma unroll
    for (int t = 0; t < 32; t++){
      float f = zm ? __bfloat162float(xa[t]) : 0.0f;
      a0 += f * wv[t * 3 + 0];
      a1 += f * wv[t * 3 + 1];
      a2 += f * wv[t * 3 + 2];
    }
    #pragma unroll
    for (int o = 1; o < 64; o <<= 1){
      a0 += __shfl_xor(a0, o, 64);
      a1 += __shfl_xor(a1, o, 64);
      a2 += __shfl_xor(a2, o, 64);
    }
    if (lane == 0){
      int ti = sr[2 * i], ai = sr[2 * i + 1], tj = sr[2 * j], aj = sr[2 * j + 1];
      bool c1 = (ai == 2) || (aj == 2);
      bool c2 = (tj == 1) || (ai == 1) || (aj == 1);
      bool c3 = (ti == 799) || (tj == 799) || (ai == 0) || (aj == 0);
      bool c4 = false;
      if (j < 13){
        int es = 28 + 4 * pe;
        c4 = (sr[es] == 1) || (sr[es + 1] == 1) || (sr[es + 2] == 1) || (sr[es + 3] == 1);
      }
      bool m1 = c3 || c4, m2 = m1 || c2, m3 = m2 || c1;
      float* op = out + ((size_t)b * 91 + p) * 3;
      op[0] = m1 ? -1.0e9f : (a0 + bl0);
      op[1] = m2 ? -1.0e9f : (a1 + bl1);
      op[2] = m3 ? -1.0e9f : (a2 + bl2);
    }
  }
}

extern "C" void kernel_launch(void* const* d_in, const int* in_sizes, int n_in,
                              void* d_out, int out_size, void* d_ws, size_t ws_size,
                              hipStream_t stream)
{
  const int*   src = (const int*)  d_in[0];
  const float* emb = (const float*)d_in[1];
  const float* wq  = (const float*)d_in[2];  const float* bq = (const float*)d_in[3];
  const float* wk  = (const float*)d_in[4];  const float* bk = (const float*)d_in[5];
  const float* wv  = (const float*)d_in[6];  const float* bv = (const float*)d_in[7];
  const float* wo  = (const float*)d_in[8];  const float* bo = (const float*)d_in[9];
  const float* n1a = (const float*)d_in[10]; const float* n1b = (const float*)d_in[11];
  const float* n2a = (const float*)d_in[12]; const float* n2b = (const float*)d_in[13];
  const float* w1  = (const float*)d_in[14]; const float* b1 = (const float*)d_in[15];
  const float* w2  = (const float*)d_in[16]; const float* b2 = (const float*)d_in[17];
  const float* wl  = (const float*)d_in[18]; const float* bl = (const float*)d_in[19];
  float* out = (float*)d_out;

  if (ws_size < 191365120ull) return;

  char* ws = (char*)d_ws;
  bf16*  x    = (bf16*)(ws);
  uchar* xn8  = (uchar*)(ws + 47185920ull);
  char*  R    = ws + 70778880ull;
  uchar* q8   = (uchar*)(R);
  uchar* vt8  = (uchar*)(R + 47185920ull);
  uchar* h8   = (uchar*)(R);
  char*  wC   = ws + 141557760ull;
  uchar* wqkv8 = (uchar*)(wC);
  uchar* wo8   = (uchar*)(wC + 196608);
  uchar* w1f8T = (uchar*)(wC + 262144);
  uchar* w2f8T = (uchar*)(wC + 786432);

  cvt_all<<<1280, 256, 0, stream>>>(wq, wk, wv, wo, w1, w2,
                                    wqkv8, wqkv8 + 65536, wqkv8 + 131072,
                                    wo8, w1f8T, w2f8T);

  embed_ln1<<<23040, 256, 0, stream>>>(src, emb, n1a, n1b, x, xn8);

  gemm_f8<4><<<2880, 256, 0, stream>>>(xn8, 256, wqkv8, 256, nullptr, q8, nullptr,
                                       512, 256, 4, bq, bk);
  gemm_f8<5><<<1440, 256, 0, stream>>>(xn8, 256, wqkv8 + 131072, 256, bv, vt8, nullptr,
                                       256, 256, 2, nullptr, nullptr);

  attn5<<<1024, 512, 0, stream>>>(q8, q8 + 23592960ull, vt8, src, xn8 /* ctx8 */);

  gemm_f8<3><<<1440, 256, 0, stream>>>(xn8, 256, wo8, 256, bo, nullptr, x,
                                       256, 256, 2, nullptr, nullptr);

  ln_k8<<<23040, 256, 0, stream>>>(x, n2a, n2b, xn8);

  for (int mc = 0; mc < 4; mc++){
    const uchar* xnc = xn8 + (size_t)mc * 23040 * 256;
    bf16* xc = x + (size_t)mc * 23040 * 256;
    gemm_f8<2><<<2880, 256, 0, stream>>>(xnc, 256, w1f8T, 256, b1, h8, nullptr,
                                         2048, 256, 16, nullptr, nullptr);
    gemm_f8<3><<<360, 256, 0, stream>>>(h8, 2048, w2f8T, 2048, b2, nullptr, xc,
                                        256, 2048, 2, nullptr, nullptr);
  }

  head_k<<<256, 256, 0, stream>>>(x, src, wl, bl, out);
}